// Round 1
// baseline (701.940 us; speedup 1.0000x reference)
//
#include <hip/hip_runtime.h>
#include <stdint.h>

// Problem constants (match reference)
#define NE   64      // experts
#define HD   2048    // hidden dim
#define ND   512     // difficulty head inner dim
#define NTOK 16384   // B*S = 4*4096

typedef __attribute__((ext_vector_type(4))) float  fv4;
typedef __attribute__((ext_vector_type(8))) short  bf16x8;
typedef __attribute__((ext_vector_type(4))) float  f32x4;

// ---------- helpers ----------
__device__ inline unsigned short bf_rne(float x) {
  unsigned int u = __float_as_uint(x);
  return (unsigned short)((u + 0x7FFFu + ((u >> 16) & 1u)) >> 16);
}
__device__ inline float bf_to_f(unsigned short h) {
  return __uint_as_float((unsigned int)h << 16);
}

// ---------- K0: zero workspace ----------
__global__ void k_zero(uint4* __restrict__ p, int n16) {
  uint4 z = {0u, 0u, 0u, 0u};
  for (int i = blockIdx.x * blockDim.x + threadIdx.x; i < n16;
       i += gridDim.x * blockDim.x)
    p[i] = z;
}

// ---------- K1: gate logits, fp64 accumulation ----------
// grid (4 ksplit, 128 token-tiles), block 128 (2 waves)
// tile: 128 tokens x 64 experts, per-thread 8x8 micro-tile, K-chunk 32
#define G_KSPLIT 4
#define G_KSEG   (HD / G_KSPLIT)   // 512
#define G_KB     32
__global__ __launch_bounds__(128, 1)
void k_gate(const float* __restrict__ hs, const float* __restrict__ gw,
            double* __restrict__ lg) {
  __shared__ float sA[128 * G_KB];   // XOR-swizzled 4-float units
  __shared__ float sB[64 * G_KB];
  const int t = threadIdx.x;
  const int ksBase = blockIdx.x * G_KSEG;
  const int tokBase = blockIdx.y * 128;
  const int tx = t & 7;        // expert octet
  const int ty = t >> 3;       // token octet (0..15)

  double acc[8][8] = {};

  for (int kb = 0; kb < G_KSEG / G_KB; ++kb) {
    const int k0 = ksBase + kb * G_KB;
    // stage A: 128 rows x 32 k, units of 4 floats, swizzle key (row>>3)&7
#pragma unroll
    for (int it = 0; it < 8; ++it) {
      int idx = t + it * 128;
      int row = idx >> 3, u = idx & 7;
      fv4 v = *(const fv4*)(hs + (size_t)(tokBase + row) * HD + k0 + u * 4);
      *(fv4*)&sA[row * 32 + ((u ^ ((row >> 3) & 7)) * 4)] = v;
    }
    // stage B: 64 rows x 32 k
#pragma unroll
    for (int it = 0; it < 4; ++it) {
      int idx = t + it * 128;
      int row = idx >> 3, u = idx & 7;
      fv4 v = *(const fv4*)(gw + (size_t)row * HD + k0 + u * 4);
      *(fv4*)&sB[row * 32 + ((u ^ ((row >> 3) & 7)) * 4)] = v;
    }
    __syncthreads();
#pragma unroll
    for (int k4 = 0; k4 < 8; ++k4) {
      fv4 av[8], bv[8];
#pragma unroll
      for (int i = 0; i < 8; ++i)
        av[i] = *(const fv4*)&sA[(8 * ty + i) * 32 + ((k4 ^ (ty & 7)) * 4)];
#pragma unroll
      for (int j = 0; j < 8; ++j)
        bv[j] = *(const fv4*)&sB[(8 * tx + j) * 32 + ((k4 ^ tx) * 4)];
#pragma unroll
      for (int kk = 0; kk < 4; ++kk) {
        double ad[8], bd[8];
#pragma unroll
        for (int i = 0; i < 8; ++i) ad[i] = (double)av[i][kk];
#pragma unroll
        for (int j = 0; j < 8; ++j) bd[j] = (double)bv[j][kk];
#pragma unroll
        for (int i = 0; i < 8; ++i)
#pragma unroll
          for (int j = 0; j < 8; ++j)
            acc[i][j] = __builtin_fma(ad[i], bd[j], acc[i][j]);
      }
    }
    __syncthreads();
  }
#pragma unroll
  for (int i = 0; i < 8; ++i)
#pragma unroll
    for (int j = 0; j < 8; ++j)
      unsafeAtomicAdd(&lg[(size_t)(tokBase + 8 * ty + i) * NE + 8 * tx + j],
                      acc[i][j]);
}

// ---------- K2: difficulty head GEMM, split-bf16 3-term MFMA ----------
// grid (8 n-chunks, 64 token-tiles), block 256 (4 waves)
// tile: 256 tokens x 64 cols, KB=32; wave = 64 rows x 64 cols (4x4 16x16 tiles)
#define D_MT 256
#define D_KB 32
__global__ __launch_bounds__(256, 2)
void k_diff(const float* __restrict__ hs, const float* __restrict__ w1,
            const float* __restrict__ b1, const float* __restrict__ w2,
            float* __restrict__ x2) {
  __shared__ unsigned short sAh[D_MT * D_KB];
  __shared__ unsigned short sAl[D_MT * D_KB];
  __shared__ unsigned short sBh[64 * D_KB];
  __shared__ unsigned short sBl[64 * D_KB];

  const int t = threadIdx.x;
  const int nBase = blockIdx.x * 64;
  const int tokBase = blockIdx.y * D_MT;
  const int w = t >> 6, lane = t & 63, l15 = lane & 15, q = lane >> 4;

  f32x4 acc[4][4] = {};

  for (int kb = 0; kb < HD / D_KB; ++kb) {
    const int k0 = kb * D_KB;
    // stage A: 256 rows x 32 k as bf16 hi/lo; 16B units of 8 bf16,
    // swizzle key (row>>2)&3
#pragma unroll
    for (int it = 0; it < 4; ++it) {
      int idx = t + it * 256;
      int row = idx >> 2, u = idx & 3;
      const float* g = hs + (size_t)(tokBase + row) * HD + k0 + u * 8;
      fv4 v0 = *(const fv4*)g;
      fv4 v1 = *(const fv4*)(g + 4);
      union { unsigned short s[8]; uint4 v; } ph, pl;
#pragma unroll
      for (int j = 0; j < 8; ++j) {
        float x = (j < 4) ? v0[j] : v1[j - 4];
        unsigned short h = bf_rne(x);
        ph.s[j] = h;
        pl.s[j] = bf_rne(x - bf_to_f(h));
      }
      int up = u ^ ((row >> 2) & 3);
      *(uint4*)&sAh[row * 32 + up * 8] = ph.v;
      *(uint4*)&sAl[row * 32 + up * 8] = pl.v;
    }
    // stage B: 64 rows x 32 k (one unit per thread)
    {
      int row = t >> 2, u = t & 3;
      const float* g = w1 + (size_t)(nBase + row) * HD + k0 + u * 8;
      fv4 v0 = *(const fv4*)g;
      fv4 v1 = *(const fv4*)(g + 4);
      union { unsigned short s[8]; uint4 v; } ph, pl;
#pragma unroll
      for (int j = 0; j < 8; ++j) {
        float x = (j < 4) ? v0[j] : v1[j - 4];
        unsigned short h = bf_rne(x);
        ph.s[j] = h;
        pl.s[j] = bf_rne(x - bf_to_f(h));
      }
      int up = u ^ ((row >> 2) & 3);
      *(uint4*)&sBh[row * 32 + up * 8] = ph.v;
      *(uint4*)&sBl[row * 32 + up * 8] = pl.v;
    }
    __syncthreads();

    bf16x8 ah[4], al[4], bh[4], bl[4];
#pragma unroll
    for (int rt = 0; rt < 4; ++rt) {
      int row = w * 64 + rt * 16 + l15;
      int off = row * 32 + ((q ^ ((row >> 2) & 3)) * 8);
      ah[rt] = *(const bf16x8*)&sAh[off];
      al[rt] = *(const bf16x8*)&sAl[off];
    }
#pragma unroll
    for (int ct = 0; ct < 4; ++ct) {
      int row = ct * 16 + l15;
      int off = row * 32 + ((q ^ ((row >> 2) & 3)) * 8);
      bh[ct] = *(const bf16x8*)&sBh[off];
      bl[ct] = *(const bf16x8*)&sBl[off];
    }
#pragma unroll
    for (int rt = 0; rt < 4; ++rt)
#pragma unroll
      for (int ct = 0; ct < 4; ++ct) {
        acc[rt][ct] = __builtin_amdgcn_mfma_f32_16x16x32_bf16(ah[rt], bh[ct], acc[rt][ct], 0, 0, 0);
        acc[rt][ct] = __builtin_amdgcn_mfma_f32_16x16x32_bf16(ah[rt], bl[ct], acc[rt][ct], 0, 0, 0);
        acc[rt][ct] = __builtin_amdgcn_mfma_f32_16x16x32_bf16(al[rt], bh[ct], acc[rt][ct], 0, 0, 0);
      }
    __syncthreads();
  }

  // epilogue: x1 + b1 -> silu -> *w2 -> reduce over 64 cols -> atomic into x2
  float b1v[4], w2v[4];
#pragma unroll
  for (int ct = 0; ct < 4; ++ct) {
    int c = nBase + ct * 16 + l15;
    b1v[ct] = b1[c];
    w2v[ct] = w2[c];
  }
#pragma unroll
  for (int rt = 0; rt < 4; ++rt) {
#pragma unroll
    for (int i = 0; i < 4; ++i) {
      float s = 0.f;
#pragma unroll
      for (int ct = 0; ct < 4; ++ct) {
        float x1 = acc[rt][ct][i] + b1v[ct];
        float h1 = x1 / (1.f + expf(-x1));   // silu
        s += h1 * w2v[ct];
      }
      s += __shfl_xor(s, 1, 64);
      s += __shfl_xor(s, 2, 64);
      s += __shfl_xor(s, 4, 64);
      s += __shfl_xor(s, 8, 64);
      if (l15 == 0)
        unsafeAtomicAdd(&x2[tokBase + w * 64 + rt * 16 + q * 4 + i], s);
    }
  }
}

// ---------- K3: per-token routing (one wave = one token's 64 experts) ----------
__global__ __launch_bounds__(256)
void k_route(const double* __restrict__ lg, const float* __restrict__ x2,
             const float* __restrict__ b2, float* __restrict__ out,
             double* __restrict__ tpe, double* __restrict__ ks_es) {
  const int t = threadIdx.x, wv = t >> 6, e = t & 63;
  const int base = blockIdx.x * 64 + wv * 16;
  const float b2v = b2[0];
  double tacc = 0.0, kacc = 0.0, eacc = 0.0;

  for (int it = 0; it < 16; ++it) {
    const int tok = base + it;
    float my = (float)lg[(size_t)tok * NE + e];
    float xv = x2[tok] + b2v;
    float d = 1.f / (1.f + expf(-xv));
    float kf = 4.f + 8.f * d;
    int ki = (int)rintf(kf);           // round-half-even, matches jnp.round
    ki = min(max(ki, 4), 12);

    int r = 0;  // stable descending rank
#pragma unroll
    for (int s = 1; s < 64; ++s) {
      int src = (e + s) & 63;
      float o = __shfl(my, src, 64);
      r += (o > my || (o == my && src < e)) ? 1 : 0;
    }
    float m = my;
#pragma unroll
    for (int off = 1; off < 64; off <<= 1) m = fmaxf(m, __shfl_xor(m, off, 64));
    float ex = (r < ki) ? expf(my - m) : 0.f;
    float sm = ex;
#pragma unroll
    for (int off = 1; off < 64; off <<= 1) sm += __shfl_xor(sm, off, 64);
    float wgt = ex / sm;
    out[(size_t)tok * NE + e] = wgt;

    tacc += (double)wgt;
    kacc += (double)kf;
    eacc += (double)(d * logf(d + 1e-8f) + (1.f - d) * logf(1.f - d + 1e-8f));
  }
  unsafeAtomicAdd(&tpe[e], tacc);
  if (e == 0) {
    unsafeAtomicAdd(&ks_es[0], kacc);
    unsafeAtomicAdd(&ks_es[1], eacc);
  }
}

// ---------- K4: aux loss ----------
__global__ void k_aux(const double* __restrict__ tpe,
                      const double* __restrict__ ks_es,
                      float* __restrict__ out) {
  const int e = threadIdx.x;  // 64 threads
  double x = tpe[e];
  double s = x;
#pragma unroll
  for (int off = 1; off < 64; off <<= 1) s += __shfl_xor(s, off, 64);
  double mean = s / 64.0;
  double dv = x - mean, v = dv * dv;
#pragma unroll
  for (int off = 1; off < 64; off <<= 1) v += __shfl_xor(v, off, 64);
  double var = v / 63.0;                       // ddof=1
  double avgk = ks_es[0] / (double)NTOK;
  double kp = 8.0 - avgk;
  kp = kp > 0.0 ? kp * kp : 0.0;               // relu(BASE_K-avg_k)^2
  double bal = var / (mean + 1e-8);
  double aux = 0.01 * (kp + bal) + 0.001 * (ks_es[1] / (double)NTOK);
  if (e == 0) out[(size_t)NTOK * NE] = (float)aux;
}

// ---------- launch ----------
extern "C" void kernel_launch(void* const* d_in, const int* in_sizes, int n_in,
                              void* d_out, int out_size, void* d_ws, size_t ws_size,
                              hipStream_t stream) {
  const float* hs = (const float*)d_in[0];
  const float* gw = (const float*)d_in[1];
  const float* w1 = (const float*)d_in[2];
  const float* b1 = (const float*)d_in[3];
  const float* w2 = (const float*)d_in[4];
  const float* b2 = (const float*)d_in[5];
  float* out = (float*)d_out;

  // workspace layout (needs ~8.07 MB)
  char* ws = (char*)d_ws;
  double* lg   = (double*)ws;               // 16384*64*8 = 8,388,608
  float*  x2   = (float*)(ws + 8388608);    // 16384*4    = 65,536
  double* tpe  = (double*)(ws + 8454144);   // 64*8       = 512
  double* ks_es = (double*)(ws + 8454656);  // 2*8        = 16

  const int n16 = 8454672 / 16;
  k_zero<<<1040, 256, 0, stream>>>((uint4*)d_ws, n16);
  k_gate<<<dim3(G_KSPLIT, NTOK / 128), 128, 0, stream>>>(hs, gw, lg);
  k_diff<<<dim3(ND / 64, NTOK / D_MT), 256, 0, stream>>>(hs, w1, b1, w2, x2);
  k_route<<<NTOK / 64, 256, 0, stream>>>(lg, x2, b2, out, tpe, ks_es);
  k_aux<<<1, 64, 0, stream>>>(tpe, ks_es, out);
}